// Round 1
// baseline (443.681 us; speedup 1.0000x reference)
//
#include <hip/hip_runtime.h>
#include <hip/hip_bf16.h>
#include <math.h>

// GCN 2-layer: x[N,128] @ W1[128,128] -> gather/scatter norm agg -> +b1,relu
//              -> @ W2[128,64] -> agg -> +b2 -> log_softmax
// N=50000, E=1,600,000 (+N self loops handled analytically)

#define WAVE 64

// ---------------- init ----------------
__global__ __launch_bounds__(256) void k_init(int* __restrict__ cnt, int* __restrict__ cursor, int n) {
    int i = blockIdx.x * 256 + threadIdx.x;
    if (i < n) { cnt[i] = 0; cursor[i] = 0; }
}

// ---------------- degree count ----------------
__global__ __launch_bounds__(256) void k_count(const int* __restrict__ edst, int* __restrict__ cnt, int e) {
    int i = blockIdx.x * 256 + threadIdx.x;
    if (i < e) atomicAdd(&cnt[edst[i]], 1);
}

// ---------------- scan phase A: block partial sums (1024 elems/block) ----------------
__global__ __launch_bounds__(256) void k_scanA(const int* __restrict__ cnt, int* __restrict__ partial, int n) {
    int tid = threadIdx.x;
    int base = blockIdx.x * 1024 + tid * 4;
    int s = 0;
#pragma unroll
    for (int t = 0; t < 4; ++t) { int idx = base + t; if (idx < n) s += cnt[idx]; }
    for (int off = 32; off; off >>= 1) s += __shfl_down(s, off);
    __shared__ int wsum[4];
    int wid = tid >> 6, lane = tid & 63;
    if (lane == 0) wsum[wid] = s;
    __syncthreads();
    if (tid == 0) partial[blockIdx.x] = wsum[0] + wsum[1] + wsum[2] + wsum[3];
}

// ---------------- scan phase B: exclusive scan of partials (single wave) ----------------
__global__ __launch_bounds__(64) void k_scanB(int* __restrict__ partial, int nb) {
    int lane = threadIdx.x;
    int v = (lane < nb) ? partial[lane] : 0;
    int x = v;
    for (int off = 1; off < 64; off <<= 1) {
        int y = __shfl_up(x, off);
        if (lane >= off) x += y;
    }
    if (lane < nb) partial[lane] = x - v;   // exclusive
}

// ---------------- scan phase C: rowstart + dinv ----------------
__global__ __launch_bounds__(256) void k_scanC(const int* __restrict__ cnt, const int* __restrict__ partial,
                                               int* __restrict__ rowstart, float* __restrict__ dinv, int n) {
    int tid = threadIdx.x;
    int base = blockIdx.x * 1024 + tid * 4;
    int v[4];
#pragma unroll
    for (int t = 0; t < 4; ++t) { int idx = base + t; v[t] = (idx < n) ? cnt[idx] : 0; }
    int tot = v[0] + v[1] + v[2] + v[3];
    int lane = tid & 63, wid = tid >> 6;
    int x = tot;
    for (int off = 1; off < 64; off <<= 1) {
        int y = __shfl_up(x, off);
        if (lane >= off) x += y;
    }
    __shared__ int wtot[4];
    if (lane == 63) wtot[wid] = x;
    __syncthreads();
    int woff = 0;
    for (int w = 0; w < wid; ++w) woff += wtot[w];
    int excl = x - tot + woff;
    int run = partial[blockIdx.x] + excl;
#pragma unroll
    for (int t = 0; t < 4; ++t) {
        int idx = base + t;
        if (idx < n) {
            rowstart[idx] = run;
            dinv[idx] = rsqrtf((float)(v[t] + 1));  // +1 self loop; deg>0 always
        }
        run += v[t];
    }
}

// ---------------- CSR fill ----------------
__global__ __launch_bounds__(256) void k_fill(const int* __restrict__ esrc, const int* __restrict__ edst,
                                              const int* __restrict__ rowstart, int* __restrict__ cursor,
                                              int* __restrict__ csr, int e) {
    int i = blockIdx.x * 256 + threadIdx.x;
    if (i >= e) return;
    int d = edst[i];
    int p = atomicAdd(&cursor[d], 1);
    csr[rowstart[d] + p] = esrc[i];
}

// ---------------- fp32 GEMM: Y[n,COLS] = X[n,128] @ W[128,COLS] ----------------
// block tile BR rows x COLS cols; per-thread TR x TC; W staged in LDS in 2 K-halves.
template <int COLS, int BR, int TR, int TC>
__global__ __launch_bounds__(256) void k_gemm(const float* __restrict__ X, const float* __restrict__ W,
                                              float* __restrict__ Y, int nrows) {
    constexpr int K = 128;
    constexpr int KH = 64;            // K half staged at a time
    constexpr int CT = COLS / TC;     // col-thread groups
    constexpr int RT = BR / TR;       // row-thread groups
    static_assert(CT * RT == 256, "bad tile");
    __shared__ float sW[KH * COLS];
    __shared__ float sX[BR][K + 1];   // +1 pad: kill stride-512B bank conflicts
    int tid = threadIdx.x;
    int rbase = blockIdx.x * BR;

    // load X tile (float4 global, scalar LDS stores due to pad)
    for (int i = tid * 4; i < BR * K; i += 1024) {
        int r = i >> 7, k = i & 127;
        float4 v = make_float4(0.f, 0.f, 0.f, 0.f);
        if (rbase + r < nrows) v = *(const float4*)&X[(size_t)(rbase + r) * K + k];
        sX[r][k + 0] = v.x; sX[r][k + 1] = v.y; sX[r][k + 2] = v.z; sX[r][k + 3] = v.w;
    }

    int ct = tid % CT, rt = tid / CT;
    int c0 = ct * TC, r0 = rt * TR;
    float acc[TR][TC] = {};

    for (int kb = 0; kb < K; kb += KH) {
        __syncthreads();
        for (int i = tid * 4; i < KH * COLS; i += 1024) {
            *(float4*)&sW[i] = *(const float4*)&W[kb * COLS + i];
        }
        __syncthreads();
#pragma unroll 4
        for (int k = 0; k < KH; ++k) {
            float xv[TR];
#pragma unroll
            for (int r = 0; r < TR; ++r) xv[r] = sX[r0 + r][kb + k];
#pragma unroll
            for (int c4 = 0; c4 < TC; c4 += 4) {
                float4 wv = *(float4*)&sW[k * COLS + c0 + c4];
#pragma unroll
                for (int r = 0; r < TR; ++r) {
                    acc[r][c4 + 0] = fmaf(xv[r], wv.x, acc[r][c4 + 0]);
                    acc[r][c4 + 1] = fmaf(xv[r], wv.y, acc[r][c4 + 1]);
                    acc[r][c4 + 2] = fmaf(xv[r], wv.z, acc[r][c4 + 2]);
                    acc[r][c4 + 3] = fmaf(xv[r], wv.w, acc[r][c4 + 3]);
                }
            }
        }
    }
#pragma unroll
    for (int r = 0; r < TR; ++r) {
        int row = rbase + r0 + r;
        if (row < nrows) {
#pragma unroll
            for (int c4 = 0; c4 < TC; c4 += 4) {
                *(float4*)&Y[(size_t)row * COLS + c0 + c4] =
                    make_float4(acc[r][c4], acc[r][c4 + 1], acc[r][c4 + 2], acc[r][c4 + 3]);
            }
        }
    }
}

// ---------------- conv1 aggregation: wave per node, float2/lane (128 ch) + bias + relu ------------
__global__ __launch_bounds__(256) void k_agg1(const float* __restrict__ xw, const int* __restrict__ csr,
                                              const int* __restrict__ rowstart, const int* __restrict__ cnt,
                                              const float* __restrict__ dinv, const float* __restrict__ b1,
                                              float* __restrict__ h, int n) {
    int wave = blockIdx.x * 4 + (threadIdx.x >> 6);
    int lane = threadIdx.x & 63;
    if (wave >= n) return;
    int i = wave;
    float di = dinv[i];
    const float2* xw2 = (const float2*)xw;
    float2 a = xw2[(size_t)i * 64 + lane];
    float accx = a.x * di, accy = a.y * di;   // self loop: dinv[i]*h[i]
    int beg = rowstart[i], m = cnt[i];
    int j = 0;
    for (; j + 2 <= m; j += 2) {
        int s0 = csr[beg + j], s1 = csr[beg + j + 1];
        float d0 = dinv[s0], d1 = dinv[s1];
        float2 v0 = xw2[(size_t)s0 * 64 + lane];
        float2 v1 = xw2[(size_t)s1 * 64 + lane];
        accx = fmaf(d0, v0.x, accx); accy = fmaf(d0, v0.y, accy);
        accx = fmaf(d1, v1.x, accx); accy = fmaf(d1, v1.y, accy);
    }
    if (j < m) {
        int s0 = csr[beg + j];
        float d0 = dinv[s0];
        float2 v0 = xw2[(size_t)s0 * 64 + lane];
        accx = fmaf(d0, v0.x, accx); accy = fmaf(d0, v0.y, accy);
    }
    float2 bb = ((const float2*)b1)[lane];
    float ox = fmaxf(fmaf(di, accx, bb.x), 0.f);
    float oy = fmaxf(fmaf(di, accy, bb.y), 0.f);
    ((float2*)h)[(size_t)i * 64 + lane] = make_float2(ox, oy);
}

// ------------- conv2 aggregation: wave per node, 1 float/lane (64 ch) + bias + log_softmax --------
__global__ __launch_bounds__(256) void k_agg2(const float* __restrict__ hw, const int* __restrict__ csr,
                                              const int* __restrict__ rowstart, const int* __restrict__ cnt,
                                              const float* __restrict__ dinv, const float* __restrict__ b2,
                                              float* __restrict__ out, int n) {
    int wave = blockIdx.x * 4 + (threadIdx.x >> 6);
    int lane = threadIdx.x & 63;
    if (wave >= n) return;
    int i = wave;
    float di = dinv[i];
    float acc = hw[(size_t)i * 64 + lane] * di;   // self loop
    int beg = rowstart[i], m = cnt[i];
    int j = 0;
    for (; j + 2 <= m; j += 2) {
        int s0 = csr[beg + j], s1 = csr[beg + j + 1];
        float d0 = dinv[s0], d1 = dinv[s1];
        float v0 = hw[(size_t)s0 * 64 + lane];
        float v1 = hw[(size_t)s1 * 64 + lane];
        acc = fmaf(d0, v0, acc);
        acc = fmaf(d1, v1, acc);
    }
    if (j < m) {
        int s0 = csr[beg + j];
        acc = fmaf(dinv[s0], hw[(size_t)s0 * 64 + lane], acc);
    }
    float o = fmaf(di, acc, b2[lane]);
    // log_softmax across the 64 lanes
    float mx = o;
    for (int off = 32; off; off >>= 1) mx = fmaxf(mx, __shfl_xor(mx, off));
    float ex = expf(o - mx);
    float sum = ex;
    for (int off = 32; off; off >>= 1) sum += __shfl_xor(sum, off);
    out[(size_t)i * 64 + lane] = o - mx - logf(sum);
}

extern "C" void kernel_launch(void* const* d_in, const int* in_sizes, int n_in,
                              void* d_out, int out_size, void* d_ws, size_t ws_size,
                              hipStream_t stream) {
    const float* x  = (const float*)d_in[0];
    const int* eidx = (const int*)d_in[1];
    const float* W1 = (const float*)d_in[2];
    const float* b1 = (const float*)d_in[3];
    const float* W2 = (const float*)d_in[4];
    const float* b2 = (const float*)d_in[5];
    float* out = (float*)d_out;

    const int n = in_sizes[0] / 128;       // 50000
    const int e = in_sizes[1] / 2;         // 1,600,000
    const int* esrc = eidx;
    const int* edst = eidx + e;

    // workspace carve-up (256B aligned)
    size_t off = 0;
    auto carve = [&](size_t bytes) {
        void* p = (char*)d_ws + off;
        off += (bytes + 255) & ~(size_t)255;
        return p;
    };
    float* xW1     = (float*)carve((size_t)n * 128 * 4);
    float* h       = (float*)carve((size_t)n * 128 * 4);
    float* hW2     = (float*)carve((size_t)n * 64 * 4);
    int*   cnt     = (int*)carve((size_t)n * 4);
    float* dinv    = (float*)carve((size_t)n * 4);
    int*   rowstart= (int*)carve((size_t)n * 4);
    int*   cursor  = (int*)carve((size_t)n * 4);
    int*   partial = (int*)carve(256 * 4);
    int*   csr     = (int*)carve((size_t)e * 4);
    (void)ws_size;

    const int nb1024 = (n + 1023) / 1024;          // scan blocks (49)
    const int nbN    = (n + 255) / 256;
    const int nbE    = (e + 255) / 256;
    const int nbWave = (n + 3) / 4;                // 4 waves per 256-block

    k_init<<<nbN, 256, 0, stream>>>(cnt, cursor, n);
    k_count<<<nbE, 256, 0, stream>>>(edst, cnt, e);
    k_scanA<<<nb1024, 256, 0, stream>>>(cnt, partial, n);
    k_scanB<<<1, 64, 0, stream>>>(partial, nb1024);
    k_scanC<<<nb1024, 256, 0, stream>>>(cnt, partial, rowstart, dinv, n);
    k_fill<<<nbE, 256, 0, stream>>>(esrc, edst, rowstart, cursor, csr, e);

    // conv1: xW1 = x @ W1  (128 -> 128)
    k_gemm<128, 32, 2, 8><<<(n + 31) / 32, 256, 0, stream>>>(x, W1, xW1, n);
    k_agg1<<<nbWave, 256, 0, stream>>>(xW1, csr, rowstart, cnt, dinv, b1, h, n);

    // conv2: hW2 = h @ W2  (128 -> 64)
    k_gemm<64, 64, 2, 8><<<(n + 63) / 64, 256, 0, stream>>>(h, W2, hW2, n);
    k_agg2<<<nbWave, 256, 0, stream>>>(hW2, csr, rowstart, cnt, dinv, b2, out, n);
}

// Round 2
// 368.998 us; speedup vs baseline: 1.2024x; 1.2024x over previous
//
#include <hip/hip_runtime.h>
#include <hip/hip_bf16.h>
#include <math.h>

// GCN 2-layer: x[N,128] @ W1[128,128] -> gather/scatter norm agg -> +b1,relu
//              -> @ W2[128,64] -> agg -> +b2 -> log_softmax
// N=50000, E=1,600,000 (+N self loops handled analytically)
// Gathered feature tables (xW1, hW2) stored in bf16 to halve the random-gather
// traffic that dominates; accumulation stays f32.

typedef unsigned int uint;
typedef unsigned short ushort_t;

__device__ inline float bf_lo(uint u) { return __uint_as_float(u << 16); }
__device__ inline float bf_hi(uint u) { return __uint_as_float(u & 0xffff0000u); }
__device__ inline ushort_t f2b(float f) {
    uint u = __float_as_uint(f);
    return (ushort_t)((u + 0x7fffu + ((u >> 16) & 1u)) >> 16);   // RNE
}
__device__ inline float b2f(ushort_t s) { return __uint_as_float((uint)s << 16); }

// ---------------- init ----------------
__global__ __launch_bounds__(256) void k_init(int* __restrict__ cnt, int* __restrict__ cursor, int n) {
    int i = blockIdx.x * 256 + threadIdx.x;
    if (i < n) { cnt[i] = 0; cursor[i] = 0; }
}

// ---------------- degree count ----------------
__global__ __launch_bounds__(256) void k_count(const int* __restrict__ edst, int* __restrict__ cnt, int e) {
    int i = blockIdx.x * 256 + threadIdx.x;
    if (i < e) atomicAdd(&cnt[edst[i]], 1);
}

// ---------------- scan phase A: block partial sums (1024 elems/block) ----------------
__global__ __launch_bounds__(256) void k_scanA(const int* __restrict__ cnt, int* __restrict__ partial, int n) {
    int tid = threadIdx.x;
    int base = blockIdx.x * 1024 + tid * 4;
    int s = 0;
#pragma unroll
    for (int t = 0; t < 4; ++t) { int idx = base + t; if (idx < n) s += cnt[idx]; }
    for (int off = 32; off; off >>= 1) s += __shfl_down(s, off);
    __shared__ int wsum[4];
    int wid = tid >> 6, lane = tid & 63;
    if (lane == 0) wsum[wid] = s;
    __syncthreads();
    if (tid == 0) partial[blockIdx.x] = wsum[0] + wsum[1] + wsum[2] + wsum[3];
}

// ---------------- scan phase B: exclusive scan of partials (single wave) ----------------
__global__ __launch_bounds__(64) void k_scanB(int* __restrict__ partial, int nb) {
    int lane = threadIdx.x;
    int v = (lane < nb) ? partial[lane] : 0;
    int x = v;
    for (int off = 1; off < 64; off <<= 1) {
        int y = __shfl_up(x, off);
        if (lane >= off) x += y;
    }
    if (lane < nb) partial[lane] = x - v;   // exclusive
}

// ---------------- scan phase C: rowstart + dinv ----------------
__global__ __launch_bounds__(256) void k_scanC(const int* __restrict__ cnt, const int* __restrict__ partial,
                                               int* __restrict__ rowstart, float* __restrict__ dinv, int n) {
    int tid = threadIdx.x;
    int base = blockIdx.x * 1024 + tid * 4;
    int v[4];
#pragma unroll
    for (int t = 0; t < 4; ++t) { int idx = base + t; v[t] = (idx < n) ? cnt[idx] : 0; }
    int tot = v[0] + v[1] + v[2] + v[3];
    int lane = tid & 63, wid = tid >> 6;
    int x = tot;
    for (int off = 1; off < 64; off <<= 1) {
        int y = __shfl_up(x, off);
        if (lane >= off) x += y;
    }
    __shared__ int wtot[4];
    if (lane == 63) wtot[wid] = x;
    __syncthreads();
    int woff = 0;
    for (int w = 0; w < wid; ++w) woff += wtot[w];
    int excl = x - tot + woff;
    int run = partial[blockIdx.x] + excl;
#pragma unroll
    for (int t = 0; t < 4; ++t) {
        int idx = base + t;
        if (idx < n) {
            rowstart[idx] = run;
            dinv[idx] = rsqrtf((float)(v[t] + 1));  // +1 self loop; deg>0 always
        }
        run += v[t];
    }
}

// ---------------- CSR fill ----------------
__global__ __launch_bounds__(256) void k_fill(const int* __restrict__ esrc, const int* __restrict__ edst,
                                              const int* __restrict__ rowstart, int* __restrict__ cursor,
                                              int* __restrict__ csr, int e) {
    int i = blockIdx.x * 256 + threadIdx.x;
    if (i >= e) return;
    int d = edst[i];
    int p = atomicAdd(&cursor[d], 1);
    csr[rowstart[d] + p] = esrc[i];
}

// ---------------- fp32 GEMM -> bf16 out: Y[n,COLS] = X[n,128] @ W[128,COLS] ----------------
// block tile BR rows x COLS cols; per-thread TR x TC; W staged in LDS in 2 K-halves.
template <int COLS, int BR, int TR, int TC>
__global__ __launch_bounds__(256) void k_gemm(const float* __restrict__ X, const float* __restrict__ W,
                                              ushort_t* __restrict__ Yb, int nrows) {
    constexpr int K = 128;
    constexpr int KH = 64;            // K half staged at a time
    constexpr int CT = COLS / TC;     // col-thread groups
    constexpr int RT = BR / TR;       // row-thread groups
    static_assert(CT * RT == 256, "bad tile");
    __shared__ float sW[KH * COLS];
    __shared__ float sX[BR][K + 1];   // +1 pad: kill stride-512B bank conflicts
    int tid = threadIdx.x;
    int rbase = blockIdx.x * BR;

    // load X tile (float4 global, scalar LDS stores due to pad)
    for (int i = tid * 4; i < BR * K; i += 1024) {
        int r = i >> 7, k = i & 127;
        float4 v = make_float4(0.f, 0.f, 0.f, 0.f);
        if (rbase + r < nrows) v = *(const float4*)&X[(size_t)(rbase + r) * K + k];
        sX[r][k + 0] = v.x; sX[r][k + 1] = v.y; sX[r][k + 2] = v.z; sX[r][k + 3] = v.w;
    }

    int ct = tid % CT, rt = tid / CT;
    int c0 = ct * TC, r0 = rt * TR;
    float acc[TR][TC] = {};

    for (int kb = 0; kb < K; kb += KH) {
        __syncthreads();
        for (int i = tid * 4; i < KH * COLS; i += 1024) {
            *(float4*)&sW[i] = *(const float4*)&W[kb * COLS + i];
        }
        __syncthreads();
#pragma unroll 4
        for (int k = 0; k < KH; ++k) {
            float xv[TR];
#pragma unroll
            for (int r = 0; r < TR; ++r) xv[r] = sX[r0 + r][kb + k];
#pragma unroll
            for (int c4 = 0; c4 < TC; c4 += 4) {
                float4 wv = *(float4*)&sW[k * COLS + c0 + c4];
#pragma unroll
                for (int r = 0; r < TR; ++r) {
                    acc[r][c4 + 0] = fmaf(xv[r], wv.x, acc[r][c4 + 0]);
                    acc[r][c4 + 1] = fmaf(xv[r], wv.y, acc[r][c4 + 1]);
                    acc[r][c4 + 2] = fmaf(xv[r], wv.z, acc[r][c4 + 2]);
                    acc[r][c4 + 3] = fmaf(xv[r], wv.w, acc[r][c4 + 3]);
                }
            }
        }
    }
#pragma unroll
    for (int r = 0; r < TR; ++r) {
        int row = rbase + r0 + r;
        if (row < nrows) {
            // pack TC bf16 and store (TC=8 -> one 16B store)
            uint pk[TC / 2];
#pragma unroll
            for (int c2 = 0; c2 < TC; c2 += 2) {
                pk[c2 / 2] = (uint)f2b(acc[r][c2]) | ((uint)f2b(acc[r][c2 + 1]) << 16);
            }
            uint* dst = (uint*)&Yb[(size_t)row * COLS + c0];
#pragma unroll
            for (int q = 0; q < TC / 2; ++q) dst[q] = pk[q];
        }
    }
}

// ------- conv1 aggregation: wave per node, 2 bf16 ch/lane (128 ch), bf16 gather + bias + relu -----
__global__ __launch_bounds__(256) void k_agg1(const uint* __restrict__ xw,   // bf16x2 per uint, 64/row
                                              const int* __restrict__ csr,
                                              const int* __restrict__ rowstart, const int* __restrict__ cnt,
                                              const float* __restrict__ dinv, const float* __restrict__ b1,
                                              float* __restrict__ h, int n) {
    int i = blockIdx.x * 4 + (threadIdx.x >> 6);
    int lane = threadIdx.x & 63;
    if (i >= n) return;
    float di = dinv[i];
    uint a = xw[(size_t)i * 64 + lane];
    float accx = bf_lo(a) * di, accy = bf_hi(a) * di;   // self loop
    int beg = rowstart[i], m = cnt[i];
    int j = 0;
    for (; j + 4 <= m; j += 4) {
        int s0 = csr[beg + j], s1 = csr[beg + j + 1], s2 = csr[beg + j + 2], s3 = csr[beg + j + 3];
        float d0 = dinv[s0], d1 = dinv[s1], d2 = dinv[s2], d3 = dinv[s3];
        uint v0 = xw[(size_t)s0 * 64 + lane];
        uint v1 = xw[(size_t)s1 * 64 + lane];
        uint v2 = xw[(size_t)s2 * 64 + lane];
        uint v3 = xw[(size_t)s3 * 64 + lane];
        accx = fmaf(d0, bf_lo(v0), accx); accy = fmaf(d0, bf_hi(v0), accy);
        accx = fmaf(d1, bf_lo(v1), accx); accy = fmaf(d1, bf_hi(v1), accy);
        accx = fmaf(d2, bf_lo(v2), accx); accy = fmaf(d2, bf_hi(v2), accy);
        accx = fmaf(d3, bf_lo(v3), accx); accy = fmaf(d3, bf_hi(v3), accy);
    }
    for (; j < m; ++j) {
        int s0 = csr[beg + j];
        float d0 = dinv[s0];
        uint v0 = xw[(size_t)s0 * 64 + lane];
        accx = fmaf(d0, bf_lo(v0), accx); accy = fmaf(d0, bf_hi(v0), accy);
    }
    float2 bb = ((const float2*)b1)[lane];
    float ox = fmaxf(fmaf(di, accx, bb.x), 0.f);
    float oy = fmaxf(fmaf(di, accy, bb.y), 0.f);
    ((float2*)h)[(size_t)i * 64 + lane] = make_float2(ox, oy);
}

// ---- conv2 aggregation: wave per node, 1 bf16 ch/lane (64 ch), bf16 gather + bias + log_softmax --
__global__ __launch_bounds__(256) void k_agg2(const ushort_t* __restrict__ hw,
                                              const int* __restrict__ csr,
                                              const int* __restrict__ rowstart, const int* __restrict__ cnt,
                                              const float* __restrict__ dinv, const float* __restrict__ b2,
                                              float* __restrict__ out, int n) {
    int i = blockIdx.x * 4 + (threadIdx.x >> 6);
    int lane = threadIdx.x & 63;
    if (i >= n) return;
    float di = dinv[i];
    float acc = b2f(hw[(size_t)i * 64 + lane]) * di;   // self loop
    int beg = rowstart[i], m = cnt[i];
    int j = 0;
    for (; j + 4 <= m; j += 4) {
        int s0 = csr[beg + j], s1 = csr[beg + j + 1], s2 = csr[beg + j + 2], s3 = csr[beg + j + 3];
        float d0 = dinv[s0], d1 = dinv[s1], d2 = dinv[s2], d3 = dinv[s3];
        float v0 = b2f(hw[(size_t)s0 * 64 + lane]);
        float v1 = b2f(hw[(size_t)s1 * 64 + lane]);
        float v2 = b2f(hw[(size_t)s2 * 64 + lane]);
        float v3 = b2f(hw[(size_t)s3 * 64 + lane]);
        acc = fmaf(d0, v0, acc);
        acc = fmaf(d1, v1, acc);
        acc = fmaf(d2, v2, acc);
        acc = fmaf(d3, v3, acc);
    }
    for (; j < m; ++j) {
        int s0 = csr[beg + j];
        acc = fmaf(dinv[s0], b2f(hw[(size_t)s0 * 64 + lane]), acc);
    }
    float o = fmaf(di, acc, b2[lane]);
    // log_softmax across the 64 lanes
    float mx = o;
    for (int off = 32; off; off >>= 1) mx = fmaxf(mx, __shfl_xor(mx, off));
    float ex = expf(o - mx);
    float sum = ex;
    for (int off = 32; off; off >>= 1) sum += __shfl_xor(sum, off);
    out[(size_t)i * 64 + lane] = o - mx - logf(sum);
}

extern "C" void kernel_launch(void* const* d_in, const int* in_sizes, int n_in,
                              void* d_out, int out_size, void* d_ws, size_t ws_size,
                              hipStream_t stream) {
    const float* x  = (const float*)d_in[0];
    const int* eidx = (const int*)d_in[1];
    const float* W1 = (const float*)d_in[2];
    const float* b1 = (const float*)d_in[3];
    const float* W2 = (const float*)d_in[4];
    const float* b2 = (const float*)d_in[5];
    float* out = (float*)d_out;

    const int n = in_sizes[0] / 128;       // 50000
    const int e = in_sizes[1] / 2;         // 1,600,000
    const int* esrc = eidx;
    const int* edst = eidx + e;

    // workspace carve-up (256B aligned)
    size_t off = 0;
    auto carve = [&](size_t bytes) {
        void* p = (char*)d_ws + off;
        off += (bytes + 255) & ~(size_t)255;
        return p;
    };
    ushort_t* xW1  = (ushort_t*)carve((size_t)n * 128 * 2);   // bf16
    float* h       = (float*)carve((size_t)n * 128 * 4);
    ushort_t* hW2  = (ushort_t*)carve((size_t)n * 64 * 2);    // bf16
    int*   cnt     = (int*)carve((size_t)n * 4);
    float* dinv    = (float*)carve((size_t)n * 4);
    int*   rowstart= (int*)carve((size_t)n * 4);
    int*   cursor  = (int*)carve((size_t)n * 4);
    int*   partial = (int*)carve(256 * 4);
    int*   csr     = (int*)carve((size_t)e * 4);
    (void)ws_size;

    const int nb1024 = (n + 1023) / 1024;          // scan blocks (49)
    const int nbN    = (n + 255) / 256;
    const int nbE    = (e + 255) / 256;
    const int nbWave = (n + 3) / 4;                // 4 waves per 256-block

    k_init<<<nbN, 256, 0, stream>>>(cnt, cursor, n);
    k_count<<<nbE, 256, 0, stream>>>(edst, cnt, e);
    k_scanA<<<nb1024, 256, 0, stream>>>(cnt, partial, n);
    k_scanB<<<1, 64, 0, stream>>>(partial, nb1024);
    k_scanC<<<nb1024, 256, 0, stream>>>(cnt, partial, rowstart, dinv, n);
    k_fill<<<nbE, 256, 0, stream>>>(esrc, edst, rowstart, cursor, csr, e);

    // conv1: xW1 = bf16(x @ W1)  (128 -> 128)
    k_gemm<128, 32, 2, 8><<<(n + 31) / 32, 256, 0, stream>>>(x, W1, xW1, n);
    k_agg1<<<nbWave, 256, 0, stream>>>((const uint*)xW1, csr, rowstart, cnt, dinv, b1, h, n);

    // conv2: hW2 = bf16(h @ W2)  (128 -> 64)
    k_gemm<64, 64, 2, 8><<<(n + 63) / 64, 256, 0, stream>>>(h, W2, hW2, n);
    k_agg2<<<nbWave, 256, 0, stream>>>(hW2, csr, rowstart, cnt, dinv, b2, out, n);
}

// Round 3
// 308.639 us; speedup vs baseline: 1.4375x; 1.1956x over previous
//
#include <hip/hip_runtime.h>
#include <hip/hip_bf16.h>
#include <math.h>

// GCN 2-layer: x[N,128] @ W1[128,128] -> gather/scatter norm agg -> +b1,relu
//              -> @ W2[128,64] -> agg -> +b2 -> log_softmax
// N=50000, E=1,600,000 (+N self loops handled analytically)
// - Gathered feature tables (xW1, hW2) in bf16: halves random-gather traffic.
// - CSR built via 2-phase binning (bucket = dst>>7) so scattered writes stay
//   dense in L2 windows: kills the 16x write amplification of naive fill.

typedef unsigned int uint;
typedef unsigned short ushort_t;

#define BSH 7                    // bucket shift: 128 nodes per bucket
#define NBMAX 400                // >= ceil(50000/128)=391
#define BIN_CHUNK 8192           // edges per k_bin block

__device__ inline float bf_lo(uint u) { return __uint_as_float(u << 16); }
__device__ inline float bf_hi(uint u) { return __uint_as_float(u & 0xffff0000u); }
__device__ inline ushort_t f2b(float f) {
    uint u = __float_as_uint(f);
    return (ushort_t)((u + 0x7fffu + ((u >> 16) & 1u)) >> 16);   // RNE
}
__device__ inline float b2f(ushort_t s) { return __uint_as_float((uint)s << 16); }

// ---------------- init ----------------
__global__ __launch_bounds__(256) void k_init(int* __restrict__ cnt, int* __restrict__ bcur,
                                              int n, int nbk) {
    int i = blockIdx.x * 256 + threadIdx.x;
    if (i < n) cnt[i] = 0;
    if (i < nbk) bcur[i] = 0;
}

// ---------------- degree count (int4 loads, 4 edges/thread) ----------------
__global__ __launch_bounds__(256) void k_count(const int* __restrict__ edst, int* __restrict__ cnt, int e) {
    int i = (blockIdx.x * 256 + threadIdx.x) * 4;
    if (i + 4 <= e) {
        int4 d = *(const int4*)&edst[i];
        atomicAdd(&cnt[d.x], 1);
        atomicAdd(&cnt[d.y], 1);
        atomicAdd(&cnt[d.z], 1);
        atomicAdd(&cnt[d.w], 1);
    } else {
        for (int j = i; j < e; ++j) atomicAdd(&cnt[edst[j]], 1);
    }
}

// ---------------- scan phase A: block partial sums (1024 elems/block) ----------------
__global__ __launch_bounds__(256) void k_scanA(const int* __restrict__ cnt, int* __restrict__ partial, int n) {
    int tid = threadIdx.x;
    int base = blockIdx.x * 1024 + tid * 4;
    int s = 0;
#pragma unroll
    for (int t = 0; t < 4; ++t) { int idx = base + t; if (idx < n) s += cnt[idx]; }
    for (int off = 32; off; off >>= 1) s += __shfl_down(s, off);
    __shared__ int wsum[4];
    int wid = tid >> 6, lane = tid & 63;
    if (lane == 0) wsum[wid] = s;
    __syncthreads();
    if (tid == 0) partial[blockIdx.x] = wsum[0] + wsum[1] + wsum[2] + wsum[3];
}

// ---------------- scan phase B: exclusive scan of partials (single wave) ----------------
__global__ __launch_bounds__(64) void k_scanB(int* __restrict__ partial, int nb) {
    int lane = threadIdx.x;
    int v = (lane < nb) ? partial[lane] : 0;
    int x = v;
    for (int off = 1; off < 64; off <<= 1) {
        int y = __shfl_up(x, off);
        if (lane >= off) x += y;
    }
    if (lane < nb) partial[lane] = x - v;   // exclusive
}

// ---------------- scan phase C: rowstart + dinv ----------------
__global__ __launch_bounds__(256) void k_scanC(const int* __restrict__ cnt, const int* __restrict__ partial,
                                               int* __restrict__ rowstart, float* __restrict__ dinv, int n) {
    int tid = threadIdx.x;
    int base = blockIdx.x * 1024 + tid * 4;
    int v[4];
#pragma unroll
    for (int t = 0; t < 4; ++t) { int idx = base + t; v[t] = (idx < n) ? cnt[idx] : 0; }
    int tot = v[0] + v[1] + v[2] + v[3];
    int lane = tid & 63, wid = tid >> 6;
    int x = tot;
    for (int off = 1; off < 64; off <<= 1) {
        int y = __shfl_up(x, off);
        if (lane >= off) x += y;
    }
    __shared__ int wtot[4];
    if (lane == 63) wtot[wid] = x;
    __syncthreads();
    int woff = 0;
    for (int w = 0; w < wid; ++w) woff += wtot[w];
    int excl = x - tot + woff;
    int run = partial[blockIdx.x] + excl;
#pragma unroll
    for (int t = 0; t < 4; ++t) {
        int idx = base + t;
        if (idx < n) {
            rowstart[idx] = run;
            dinv[idx] = rsqrtf((float)(v[t] + 1));  // +1 self loop; deg>0 always
        }
        run += v[t];
    }
}

// ---------------- bin phase 1: bucket edges by dst>>BSH, coalesced-ish segment writes -----------
// bin region for bucket b starts at rowstart[b<<BSH] (csr-aligned layout).
// entry = src | (dst & 127) << 17   (src<2^17, 7-bit local dst)
__global__ __launch_bounds__(256) void k_bin(const int* __restrict__ esrc, const int* __restrict__ edst,
                                             const int* __restrict__ rowstart, int* __restrict__ bcur,
                                             uint* __restrict__ bin, int e, int nbk) {
    __shared__ int hist[NBMAX];
    __shared__ int segbase[NBMAX];
    int tid = threadIdx.x;
    int b0 = blockIdx.x * BIN_CHUNK;
    int b1 = min(b0 + BIN_CHUNK, e);
    for (int i = tid; i < nbk; i += 256) hist[i] = 0;
    __syncthreads();
    for (int i = b0 + tid; i < b1; i += 256) atomicAdd(&hist[edst[i] >> BSH], 1);
    __syncthreads();
    for (int b = tid; b < nbk; b += 256) {
        int c = hist[b];
        int gb = c ? atomicAdd(&bcur[b], c) : 0;
        segbase[b] = rowstart[b << BSH] + gb;
        hist[b] = 0;  // reuse as local cursor
    }
    __syncthreads();
    for (int i = b0 + tid; i < b1; i += 256) {
        int d = edst[i], s = esrc[i];
        int b = d >> BSH;
        int p = atomicAdd(&hist[b], 1);
        bin[segbase[b] + p] = (uint)s | ((uint)(d & 127) << 17);
    }
}

// ---------------- bin phase 2: per-bucket fine fill (L2-resident 16KB window) ----------------
__global__ __launch_bounds__(256) void k_fill2(const uint* __restrict__ bin, const int* __restrict__ rowstart,
                                               int* __restrict__ csr, int n, int e) {
    __shared__ int cur[1 << BSH];
    int b = blockIdx.x;
    int lo = b << BSH;
    int hi = min(lo + (1 << BSH), n);
    int tid = threadIdx.x;
    if (tid < hi - lo) cur[tid] = rowstart[lo + tid];
    __syncthreads();
    int base = rowstart[lo];
    int cntE = ((hi < n) ? rowstart[hi] : e) - base;
    for (int i = tid; i < cntE; i += 256) {
        uint v = bin[base + i];
        int dl = v >> 17;
        int s = (int)(v & 0x1FFFFu);
        int p = atomicAdd(&cur[dl], 1);
        csr[p] = s;
    }
}

// ---------------- fp32 GEMM -> bf16 out: Y[n,COLS] = X[n,128] @ W[128,COLS] ----------------
template <int COLS, int BR, int TR, int TC>
__global__ __launch_bounds__(256) void k_gemm(const float* __restrict__ X, const float* __restrict__ W,
                                              ushort_t* __restrict__ Yb, int nrows) {
    constexpr int K = 128;
    constexpr int KH = 64;            // K half staged at a time
    constexpr int CT = COLS / TC;     // col-thread groups
    constexpr int RT = BR / TR;       // row-thread groups
    static_assert(CT * RT == 256, "bad tile");
    __shared__ float sW[KH * COLS];
    __shared__ float sX[BR][K + 1];   // +1 pad: kill stride-512B bank conflicts
    int tid = threadIdx.x;
    int rbase = blockIdx.x * BR;

    for (int i = tid * 4; i < BR * K; i += 1024) {
        int r = i >> 7, k = i & 127;
        float4 v = make_float4(0.f, 0.f, 0.f, 0.f);
        if (rbase + r < nrows) v = *(const float4*)&X[(size_t)(rbase + r) * K + k];
        sX[r][k + 0] = v.x; sX[r][k + 1] = v.y; sX[r][k + 2] = v.z; sX[r][k + 3] = v.w;
    }

    int ct = tid % CT, rt = tid / CT;
    int c0 = ct * TC, r0 = rt * TR;
    float acc[TR][TC] = {};

    for (int kb = 0; kb < K; kb += KH) {
        __syncthreads();
        for (int i = tid * 4; i < KH * COLS; i += 1024) {
            *(float4*)&sW[i] = *(const float4*)&W[kb * COLS + i];
        }
        __syncthreads();
#pragma unroll 4
        for (int k = 0; k < KH; ++k) {
            float xv[TR];
#pragma unroll
            for (int r = 0; r < TR; ++r) xv[r] = sX[r0 + r][kb + k];
#pragma unroll
            for (int c4 = 0; c4 < TC; c4 += 4) {
                float4 wv = *(float4*)&sW[k * COLS + c0 + c4];
#pragma unroll
                for (int r = 0; r < TR; ++r) {
                    acc[r][c4 + 0] = fmaf(xv[r], wv.x, acc[r][c4 + 0]);
                    acc[r][c4 + 1] = fmaf(xv[r], wv.y, acc[r][c4 + 1]);
                    acc[r][c4 + 2] = fmaf(xv[r], wv.z, acc[r][c4 + 2]);
                    acc[r][c4 + 3] = fmaf(xv[r], wv.w, acc[r][c4 + 3]);
                }
            }
        }
    }
#pragma unroll
    for (int r = 0; r < TR; ++r) {
        int row = rbase + r0 + r;
        if (row < nrows) {
            uint pk[TC / 2];
#pragma unroll
            for (int c2 = 0; c2 < TC; c2 += 2) {
                pk[c2 / 2] = (uint)f2b(acc[r][c2]) | ((uint)f2b(acc[r][c2 + 1]) << 16);
            }
            uint* dst = (uint*)&Yb[(size_t)row * COLS + c0];
#pragma unroll
            for (int q = 0; q < TC / 2; ++q) dst[q] = pk[q];
        }
    }
}

// ------- conv1 aggregation: wave per node, 2 bf16 ch/lane (128 ch), bf16 gather + bias + relu -----
__global__ __launch_bounds__(256) void k_agg1(const uint* __restrict__ xw,   // bf16x2 per uint, 64/row
                                              const int* __restrict__ csr,
                                              const int* __restrict__ rowstart, const int* __restrict__ cnt,
                                              const float* __restrict__ dinv, const float* __restrict__ b1,
                                              float* __restrict__ h, int n) {
    int i = blockIdx.x * 4 + (threadIdx.x >> 6);
    int lane = threadIdx.x & 63;
    if (i >= n) return;
    float di = dinv[i];
    uint a = xw[(size_t)i * 64 + lane];
    float accx = bf_lo(a) * di, accy = bf_hi(a) * di;   // self loop
    int beg = rowstart[i], m = cnt[i];
    int j = 0;
    for (; j + 4 <= m; j += 4) {
        int s0 = csr[beg + j], s1 = csr[beg + j + 1], s2 = csr[beg + j + 2], s3 = csr[beg + j + 3];
        float d0 = dinv[s0], d1 = dinv[s1], d2 = dinv[s2], d3 = dinv[s3];
        uint v0 = xw[(size_t)s0 * 64 + lane];
        uint v1 = xw[(size_t)s1 * 64 + lane];
        uint v2 = xw[(size_t)s2 * 64 + lane];
        uint v3 = xw[(size_t)s3 * 64 + lane];
        accx = fmaf(d0, bf_lo(v0), accx); accy = fmaf(d0, bf_hi(v0), accy);
        accx = fmaf(d1, bf_lo(v1), accx); accy = fmaf(d1, bf_hi(v1), accy);
        accx = fmaf(d2, bf_lo(v2), accx); accy = fmaf(d2, bf_hi(v2), accy);
        accx = fmaf(d3, bf_lo(v3), accx); accy = fmaf(d3, bf_hi(v3), accy);
    }
    for (; j < m; ++j) {
        int s0 = csr[beg + j];
        float d0 = dinv[s0];
        uint v0 = xw[(size_t)s0 * 64 + lane];
        accx = fmaf(d0, bf_lo(v0), accx); accy = fmaf(d0, bf_hi(v0), accy);
    }
    float2 bb = ((const float2*)b1)[lane];
    float ox = fmaxf(fmaf(di, accx, bb.x), 0.f);
    float oy = fmaxf(fmaf(di, accy, bb.y), 0.f);
    ((float2*)h)[(size_t)i * 64 + lane] = make_float2(ox, oy);
}

// ---- conv2 aggregation: wave per node, 1 bf16 ch/lane (64 ch), bf16 gather + bias + log_softmax --
__global__ __launch_bounds__(256) void k_agg2(const ushort_t* __restrict__ hw,
                                              const int* __restrict__ csr,
                                              const int* __restrict__ rowstart, const int* __restrict__ cnt,
                                              const float* __restrict__ dinv, const float* __restrict__ b2,
                                              float* __restrict__ out, int n) {
    int i = blockIdx.x * 4 + (threadIdx.x >> 6);
    int lane = threadIdx.x & 63;
    if (i >= n) return;
    float di = dinv[i];
    float acc = b2f(hw[(size_t)i * 64 + lane]) * di;   // self loop
    int beg = rowstart[i], m = cnt[i];
    int j = 0;
    for (; j + 4 <= m; j += 4) {
        int s0 = csr[beg + j], s1 = csr[beg + j + 1], s2 = csr[beg + j + 2], s3 = csr[beg + j + 3];
        float d0 = dinv[s0], d1 = dinv[s1], d2 = dinv[s2], d3 = dinv[s3];
        float v0 = b2f(hw[(size_t)s0 * 64 + lane]);
        float v1 = b2f(hw[(size_t)s1 * 64 + lane]);
        float v2 = b2f(hw[(size_t)s2 * 64 + lane]);
        float v3 = b2f(hw[(size_t)s3 * 64 + lane]);
        acc = fmaf(d0, v0, acc);
        acc = fmaf(d1, v1, acc);
        acc = fmaf(d2, v2, acc);
        acc = fmaf(d3, v3, acc);
    }
    for (; j < m; ++j) {
        int s0 = csr[beg + j];
        acc = fmaf(dinv[s0], b2f(hw[(size_t)s0 * 64 + lane]), acc);
    }
    float o = fmaf(di, acc, b2[lane]);
    // log_softmax across the 64 lanes
    float mx = o;
    for (int off = 32; off; off >>= 1) mx = fmaxf(mx, __shfl_xor(mx, off));
    float ex = expf(o - mx);
    float sum = ex;
    for (int off = 32; off; off >>= 1) sum += __shfl_xor(sum, off);
    out[(size_t)i * 64 + lane] = o - mx - logf(sum);
}

extern "C" void kernel_launch(void* const* d_in, const int* in_sizes, int n_in,
                              void* d_out, int out_size, void* d_ws, size_t ws_size,
                              hipStream_t stream) {
    const float* x  = (const float*)d_in[0];
    const int* eidx = (const int*)d_in[1];
    const float* W1 = (const float*)d_in[2];
    const float* b1 = (const float*)d_in[3];
    const float* W2 = (const float*)d_in[4];
    const float* b2 = (const float*)d_in[5];
    float* out = (float*)d_out;

    const int n = in_sizes[0] / 128;       // 50000
    const int e = in_sizes[1] / 2;         // 1,600,000
    const int* esrc = eidx;
    const int* edst = eidx + e;
    const int nbk = (n + (1 << BSH) - 1) >> BSH;   // 391 buckets

    // workspace carve-up (256B aligned)
    size_t off = 0;
    auto carve = [&](size_t bytes) {
        void* p = (char*)d_ws + off;
        off += (bytes + 255) & ~(size_t)255;
        return p;
    };
    ushort_t* xW1  = (ushort_t*)carve((size_t)n * 128 * 2);   // bf16
    float* h       = (float*)carve((size_t)n * 128 * 4);
    ushort_t* hW2  = (ushort_t*)carve((size_t)n * 64 * 2);    // bf16
    int*   cnt     = (int*)carve((size_t)n * 4);
    float* dinv    = (float*)carve((size_t)n * 4);
    int*   rowstart= (int*)carve((size_t)n * 4);
    int*   bcur    = (int*)carve((size_t)nbk * 4);
    int*   partial = (int*)carve(256 * 4);
    uint*  bin     = (uint*)carve((size_t)e * 4);
    int*   csr     = (int*)carve((size_t)e * 4);
    (void)ws_size;

    const int nb1024 = (n + 1023) / 1024;          // scan blocks (49)
    const int nbN    = (n + 255) / 256;
    const int nbE4   = (e + 1023) / 1024;          // 4 edges/thread
    const int nbBin  = (e + BIN_CHUNK - 1) / BIN_CHUNK;
    const int nbWave = (n + 3) / 4;                // 4 waves per 256-block

    k_init<<<nbN, 256, 0, stream>>>(cnt, bcur, n, nbk);
    k_count<<<nbE4, 256, 0, stream>>>(edst, cnt, e);
    k_scanA<<<nb1024, 256, 0, stream>>>(cnt, partial, n);
    k_scanB<<<1, 64, 0, stream>>>(partial, nb1024);
    k_scanC<<<nb1024, 256, 0, stream>>>(cnt, partial, rowstart, dinv, n);
    k_bin<<<nbBin, 256, 0, stream>>>(esrc, edst, rowstart, bcur, bin, e, nbk);
    k_fill2<<<nbk, 256, 0, stream>>>(bin, rowstart, csr, n, e);

    // conv1: xW1 = bf16(x @ W1)  (128 -> 128)
    k_gemm<128, 32, 2, 8><<<(n + 31) / 32, 256, 0, stream>>>(x, W1, xW1, n);
    k_agg1<<<nbWave, 256, 0, stream>>>((const uint*)xW1, csr, rowstart, cnt, dinv, b1, h, n);

    // conv2: hW2 = bf16(h @ W2)  (128 -> 64)
    k_gemm<64, 64, 2, 8><<<(n + 63) / 64, 256, 0, stream>>>(h, W2, hW2, n);
    k_agg2<<<nbWave, 256, 0, stream>>>(hW2, csr, rowstart, cnt, dinv, b2, out, n);
}

// Round 4
// 235.345 us; speedup vs baseline: 1.8852x; 1.3114x over previous
//
#include <hip/hip_runtime.h>
#include <hip/hip_bf16.h>
#include <math.h>

// GCN 2-layer: x[N,128] @ W1[128,128] -> gather/scatter norm agg -> +b1,relu
//              -> @ W2[128,64] -> agg -> +b2 -> log_softmax
// N=50000, E=1,600,000 (+N self loops handled analytically)
// - Gathered feature tables (xW1, hW2) in bf16: halves random-gather traffic.
// - Graph build with ZERO per-edge global atomics:
//     k_bin:    LDS-histogram binning by dst>>7 into fixed-capacity bucket bins
//     k_scanBkt: 391-entry scan -> bucket CSR bases
//     k_bucket: per-bucket LDS count+scan -> rowstart/cnt/dinv + L2-window csr scatter

typedef unsigned int uint;
typedef unsigned short ushort_t;

#define BSH 7                    // bucket shift: 128 nodes per bucket
#define NBMAX 400                // >= ceil(50000/128)=391
#define BIN_CHUNK 16384          // edges per k_bin block
#define CAP 6144                 // bin capacity per bucket (expected 4092, sd ~64)

__device__ inline float bf_lo(uint u) { return __uint_as_float(u << 16); }
__device__ inline float bf_hi(uint u) { return __uint_as_float(u & 0xffff0000u); }
__device__ inline ushort_t f2b(float f) {
    uint u = __float_as_uint(f);
    return (ushort_t)((u + 0x7fffu + ((u >> 16) & 1u)) >> 16);   // RNE
}
__device__ inline float b2f(ushort_t s) { return __uint_as_float((uint)s << 16); }

// ---------------- init: zero bucket counters ----------------
__global__ __launch_bounds__(256) void k_init(int* __restrict__ bktcnt, int nbk) {
    int i = blockIdx.x * 256 + threadIdx.x;
    if (i < nbk) bktcnt[i] = 0;
}

// ---------------- bin: bucket edges by dst>>BSH (LDS hist; block-segment writes) ----------------
// bucket b's region is bin[b*CAP .. ); entry = src | (dst & 127) << 17
__global__ __launch_bounds__(256) void k_bin(const int* __restrict__ esrc, const int* __restrict__ edst,
                                             int* __restrict__ bktcnt, uint* __restrict__ bin,
                                             int e, int nbk) {
    __shared__ int hist[NBMAX];
    __shared__ int segbase[NBMAX];
    int tid = threadIdx.x;
    int b0 = blockIdx.x * BIN_CHUNK;
    int b1 = min(b0 + BIN_CHUNK, e);
    for (int i = tid; i < nbk; i += 256) hist[i] = 0;
    __syncthreads();
    for (int i = b0 + tid * 4; i < b1; i += 1024) {
        if (i + 4 <= b1) {
            int4 d = *(const int4*)&edst[i];
            atomicAdd(&hist[d.x >> BSH], 1);
            atomicAdd(&hist[d.y >> BSH], 1);
            atomicAdd(&hist[d.z >> BSH], 1);
            atomicAdd(&hist[d.w >> BSH], 1);
        } else {
            for (int j = i; j < b1; ++j) atomicAdd(&hist[edst[j] >> BSH], 1);
        }
    }
    __syncthreads();
    for (int b = tid; b < nbk; b += 256) {
        int c = hist[b];
        int gb = c ? atomicAdd(&bktcnt[b], c) : 0;
        segbase[b] = b * CAP + gb;
        hist[b] = 0;  // reuse as local cursor
    }
    __syncthreads();
    for (int i = b0 + tid * 4; i < b1; i += 1024) {
        if (i + 4 <= b1) {
            int4 d = *(const int4*)&edst[i];
            int4 s = *(const int4*)&esrc[i];
            int bx = d.x >> BSH, by = d.y >> BSH, bz = d.z >> BSH, bw = d.w >> BSH;
            int px = atomicAdd(&hist[bx], 1);
            int py = atomicAdd(&hist[by], 1);
            int pz = atomicAdd(&hist[bz], 1);
            int pw = atomicAdd(&hist[bw], 1);
            bin[segbase[bx] + px] = (uint)s.x | ((uint)(d.x & 127) << 17);
            bin[segbase[by] + py] = (uint)s.y | ((uint)(d.y & 127) << 17);
            bin[segbase[bz] + pz] = (uint)s.z | ((uint)(d.z & 127) << 17);
            bin[segbase[bw] + pw] = (uint)s.w | ((uint)(d.w & 127) << 17);
        } else {
            for (int j = i; j < b1; ++j) {
                int d = edst[j], s = esrc[j];
                int b = d >> BSH;
                int p = atomicAdd(&hist[b], 1);
                bin[segbase[b] + p] = (uint)s | ((uint)(d & 127) << 17);
            }
        }
    }
}

// ---------------- scan of 391 bucket counts -> bucket CSR bases (one block) ----------------
__global__ __launch_bounds__(512) void k_scanBkt(const int* __restrict__ bktcnt, int* __restrict__ bktoff,
                                                 int nbk) {
    int tid = threadIdx.x;
    int v = (tid < nbk) ? bktcnt[tid] : 0;
    int x = v;
    for (int off = 1; off < 64; off <<= 1) {
        int y = __shfl_up(x, off);
        if ((tid & 63) >= off) x += y;
    }
    __shared__ int wt[8];
    if ((tid & 63) == 63) wt[tid >> 6] = x;
    __syncthreads();
    int w = tid >> 6, woff = 0;
    for (int k = 0; k < w; ++k) woff += wt[k];
    if (tid < nbk) bktoff[tid] = x - v + woff;
}

// ---------------- per-bucket: count/scan/scatter inside an L2-resident window ----------------
__global__ __launch_bounds__(256) void k_bucket(const uint* __restrict__ bin, const int* __restrict__ bktcnt,
                                                const int* __restrict__ bktoff,
                                                int* __restrict__ rowstart, int* __restrict__ cnt,
                                                float* __restrict__ dinv, int* __restrict__ csr, int n) {
    __shared__ int lcnt[1 << BSH];
    __shared__ int cur[1 << BSH];
    __shared__ int wt[4];
    int b = blockIdx.x;
    int tid = threadIdx.x;
    int lo = b << BSH;
    int nl = min(1 << BSH, n - lo);
    int m = bktcnt[b];
    int base = b * CAP;
    int obase = bktoff[b];
    if (tid < (1 << BSH)) lcnt[tid] = 0;
    __syncthreads();
    for (int i = tid; i < m; i += 256) {
        uint v = bin[base + i];
        atomicAdd(&lcnt[v >> 17], 1);
    }
    __syncthreads();
    int v = (tid < (1 << BSH)) ? lcnt[tid] : 0;
    int x = v;
    for (int off = 1; off < 64; off <<= 1) {
        int y = __shfl_up(x, off);
        if ((tid & 63) >= off) x += y;
    }
    if ((tid & 63) == 63) wt[tid >> 6] = x;
    __syncthreads();
    int excl = x - v + ((tid >= 64 && tid < 128) ? wt[0] : 0);
    if (tid < nl) {
        int node = lo + tid;
        rowstart[node] = obase + excl;
        cnt[node] = v;
        dinv[node] = rsqrtf((float)(v + 1));   // +1 self loop
        cur[tid] = obase + excl;
    }
    __syncthreads();
    for (int i = tid; i < m; i += 256) {
        uint en = bin[base + i];
        int dl = en >> 17;
        int p = atomicAdd(&cur[dl], 1);
        csr[p] = (int)(en & 0x1FFFFu);
    }
}

// ---------------- fp32 GEMM -> bf16 out: Y[n,COLS] = X[n,128] @ W[128,COLS] ----------------
template <int COLS, int BR, int TR, int TC>
__global__ __launch_bounds__(256) void k_gemm(const float* __restrict__ X, const float* __restrict__ W,
                                              ushort_t* __restrict__ Yb, int nrows) {
    constexpr int K = 128;
    constexpr int KH = 64;            // K half staged at a time
    constexpr int CT = COLS / TC;     // col-thread groups
    constexpr int RT = BR / TR;       // row-thread groups
    static_assert(CT * RT == 256, "bad tile");
    __shared__ float sW[KH * COLS];
    __shared__ float sX[BR][K + 1];   // +1 pad: kill stride-512B bank conflicts
    int tid = threadIdx.x;
    int rbase = blockIdx.x * BR;

    for (int i = tid * 4; i < BR * K; i += 1024) {
        int r = i >> 7, k = i & 127;
        float4 v = make_float4(0.f, 0.f, 0.f, 0.f);
        if (rbase + r < nrows) v = *(const float4*)&X[(size_t)(rbase + r) * K + k];
        sX[r][k + 0] = v.x; sX[r][k + 1] = v.y; sX[r][k + 2] = v.z; sX[r][k + 3] = v.w;
    }

    int ct = tid % CT, rt = tid / CT;
    int c0 = ct * TC, r0 = rt * TR;
    float acc[TR][TC] = {};

    for (int kb = 0; kb < K; kb += KH) {
        __syncthreads();
        for (int i = tid * 4; i < KH * COLS; i += 1024) {
            *(float4*)&sW[i] = *(const float4*)&W[kb * COLS + i];
        }
        __syncthreads();
#pragma unroll 4
        for (int k = 0; k < KH; ++k) {
            float xv[TR];
#pragma unroll
            for (int r = 0; r < TR; ++r) xv[r] = sX[r0 + r][kb + k];
#pragma unroll
            for (int c4 = 0; c4 < TC; c4 += 4) {
                float4 wv = *(float4*)&sW[k * COLS + c0 + c4];
#pragma unroll
                for (int r = 0; r < TR; ++r) {
                    acc[r][c4 + 0] = fmaf(xv[r], wv.x, acc[r][c4 + 0]);
                    acc[r][c4 + 1] = fmaf(xv[r], wv.y, acc[r][c4 + 1]);
                    acc[r][c4 + 2] = fmaf(xv[r], wv.z, acc[r][c4 + 2]);
                    acc[r][c4 + 3] = fmaf(xv[r], wv.w, acc[r][c4 + 3]);
                }
            }
        }
    }
#pragma unroll
    for (int r = 0; r < TR; ++r) {
        int row = rbase + r0 + r;
        if (row < nrows) {
            uint pk[TC / 2];
#pragma unroll
            for (int c2 = 0; c2 < TC; c2 += 2) {
                pk[c2 / 2] = (uint)f2b(acc[r][c2]) | ((uint)f2b(acc[r][c2 + 1]) << 16);
            }
            uint* dst = (uint*)&Yb[(size_t)row * COLS + c0];
#pragma unroll
            for (int q = 0; q < TC / 2; ++q) dst[q] = pk[q];
        }
    }
}

// ------- conv1 aggregation: wave per node, 2 bf16 ch/lane (128 ch), bf16 gather + bias + relu -----
__global__ __launch_bounds__(256) void k_agg1(const uint* __restrict__ xw,   // bf16x2 per uint, 64/row
                                              const int* __restrict__ csr,
                                              const int* __restrict__ rowstart, const int* __restrict__ cnt,
                                              const float* __restrict__ dinv, const float* __restrict__ b1,
                                              float* __restrict__ h, int n) {
    int i = blockIdx.x * 4 + (threadIdx.x >> 6);
    int lane = threadIdx.x & 63;
    if (i >= n) return;
    float di = dinv[i];
    uint a = xw[(size_t)i * 64 + lane];
    float accx = bf_lo(a) * di, accy = bf_hi(a) * di;   // self loop
    int beg = rowstart[i], m = cnt[i];
    int j = 0;
    for (; j + 4 <= m; j += 4) {
        int s0 = csr[beg + j], s1 = csr[beg + j + 1], s2 = csr[beg + j + 2], s3 = csr[beg + j + 3];
        float d0 = dinv[s0], d1 = dinv[s1], d2 = dinv[s2], d3 = dinv[s3];
        uint v0 = xw[(size_t)s0 * 64 + lane];
        uint v1 = xw[(size_t)s1 * 64 + lane];
        uint v2 = xw[(size_t)s2 * 64 + lane];
        uint v3 = xw[(size_t)s3 * 64 + lane];
        accx = fmaf(d0, bf_lo(v0), accx); accy = fmaf(d0, bf_hi(v0), accy);
        accx = fmaf(d1, bf_lo(v1), accx); accy = fmaf(d1, bf_hi(v1), accy);
        accx = fmaf(d2, bf_lo(v2), accx); accy = fmaf(d2, bf_hi(v2), accy);
        accx = fmaf(d3, bf_lo(v3), accx); accy = fmaf(d3, bf_hi(v3), accy);
    }
    for (; j < m; ++j) {
        int s0 = csr[beg + j];
        float d0 = dinv[s0];
        uint v0 = xw[(size_t)s0 * 64 + lane];
        accx = fmaf(d0, bf_lo(v0), accx); accy = fmaf(d0, bf_hi(v0), accy);
    }
    float2 bb = ((const float2*)b1)[lane];
    float ox = fmaxf(fmaf(di, accx, bb.x), 0.f);
    float oy = fmaxf(fmaf(di, accy, bb.y), 0.f);
    ((float2*)h)[(size_t)i * 64 + lane] = make_float2(ox, oy);
}

// ---- conv2 aggregation: wave per node, 1 bf16 ch/lane (64 ch), bf16 gather + bias + log_softmax --
__global__ __launch_bounds__(256) void k_agg2(const ushort_t* __restrict__ hw,
                                              const int* __restrict__ csr,
                                              const int* __restrict__ rowstart, const int* __restrict__ cnt,
                                              const float* __restrict__ dinv, const float* __restrict__ b2,
                                              float* __restrict__ out, int n) {
    int i = blockIdx.x * 4 + (threadIdx.x >> 6);
    int lane = threadIdx.x & 63;
    if (i >= n) return;
    float di = dinv[i];
    float acc = b2f(hw[(size_t)i * 64 + lane]) * di;   // self loop
    int beg = rowstart[i], m = cnt[i];
    int j = 0;
    for (; j + 4 <= m; j += 4) {
        int s0 = csr[beg + j], s1 = csr[beg + j + 1], s2 = csr[beg + j + 2], s3 = csr[beg + j + 3];
        float d0 = dinv[s0], d1 = dinv[s1], d2 = dinv[s2], d3 = dinv[s3];
        float v0 = b2f(hw[(size_t)s0 * 64 + lane]);
        float v1 = b2f(hw[(size_t)s1 * 64 + lane]);
        float v2 = b2f(hw[(size_t)s2 * 64 + lane]);
        float v3 = b2f(hw[(size_t)s3 * 64 + lane]);
        acc = fmaf(d0, v0, acc);
        acc = fmaf(d1, v1, acc);
        acc = fmaf(d2, v2, acc);
        acc = fmaf(d3, v3, acc);
    }
    for (; j < m; ++j) {
        int s0 = csr[beg + j];
        acc = fmaf(dinv[s0], b2f(hw[(size_t)s0 * 64 + lane]), acc);
    }
    float o = fmaf(di, acc, b2[lane]);
    // log_softmax across the 64 lanes
    float mx = o;
    for (int off = 32; off; off >>= 1) mx = fmaxf(mx, __shfl_xor(mx, off));
    float ex = expf(o - mx);
    float sum = ex;
    for (int off = 32; off; off >>= 1) sum += __shfl_xor(sum, off);
    out[(size_t)i * 64 + lane] = o - mx - logf(sum);
}

extern "C" void kernel_launch(void* const* d_in, const int* in_sizes, int n_in,
                              void* d_out, int out_size, void* d_ws, size_t ws_size,
                              hipStream_t stream) {
    const float* x  = (const float*)d_in[0];
    const int* eidx = (const int*)d_in[1];
    const float* W1 = (const float*)d_in[2];
    const float* b1 = (const float*)d_in[3];
    const float* W2 = (const float*)d_in[4];
    const float* b2 = (const float*)d_in[5];
    float* out = (float*)d_out;

    const int n = in_sizes[0] / 128;       // 50000
    const int e = in_sizes[1] / 2;         // 1,600,000
    const int* esrc = eidx;
    const int* edst = eidx + e;
    const int nbk = (n + (1 << BSH) - 1) >> BSH;   // 391 buckets

    // workspace carve-up (256B aligned)
    size_t off = 0;
    auto carve = [&](size_t bytes) {
        void* p = (char*)d_ws + off;
        off += (bytes + 255) & ~(size_t)255;
        return p;
    };
    ushort_t* xW1  = (ushort_t*)carve((size_t)n * 128 * 2);   // bf16
    float* h       = (float*)carve((size_t)n * 128 * 4);
    ushort_t* hW2  = (ushort_t*)carve((size_t)n * 64 * 2);    // bf16
    int*   cnt     = (int*)carve((size_t)n * 4);
    float* dinv    = (float*)carve((size_t)n * 4);
    int*   rowstart= (int*)carve((size_t)n * 4);
    int*   bktcnt  = (int*)carve((size_t)nbk * 4);
    int*   bktoff  = (int*)carve((size_t)nbk * 4);
    uint*  bin     = (uint*)carve((size_t)nbk * CAP * 4);
    int*   csr     = (int*)carve((size_t)e * 4);
    (void)ws_size;

    const int nbBin  = (e + BIN_CHUNK - 1) / BIN_CHUNK;
    const int nbWave = (n + 3) / 4;                // 4 waves per 256-block

    k_init<<<(nbk + 255) / 256, 256, 0, stream>>>(bktcnt, nbk);
    k_bin<<<nbBin, 256, 0, stream>>>(esrc, edst, bktcnt, bin, e, nbk);
    k_scanBkt<<<1, 512, 0, stream>>>(bktcnt, bktoff, nbk);
    k_bucket<<<nbk, 256, 0, stream>>>(bin, bktcnt, bktoff, rowstart, cnt, dinv, csr, n);

    // conv1: xW1 = bf16(x @ W1)  (128 -> 128)
    k_gemm<128, 32, 2, 8><<<(n + 31) / 32, 256, 0, stream>>>(x, W1, xW1, n);
    k_agg1<<<nbWave, 256, 0, stream>>>((const uint*)xW1, csr, rowstart, cnt, dinv, b1, h, n);

    // conv2: hW2 = bf16(h @ W2)  (128 -> 64)
    k_gemm<64, 64, 2, 8><<<(n + 63) / 64, 256, 0, stream>>>(h, W2, hW2, n);
    k_agg2<<<nbWave, 256, 0, stream>>>(hW2, csr, rowstart, cnt, dinv, b2, out, n);
}